// Round 3
// baseline (923.812 us; speedup 1.0000x reference)
//
#include <hip/hip_runtime.h>

#define NPTS   300000
#define NPAIRS 100000
#define KOFF   27
#define NTOT   (KOFF * NPAIRS)
#define CIN    32
#define COUT   64
#define NGROUP 8
#define EPSV   1e-5f
#define SLOPE  0.01f

#define PAIRS_PER_BLOCK 256
#define BLOCKS_PER_K ((NPAIRS + PAIRS_PER_BLOCK - 1) / PAIRS_PER_BLOCK)  /* 391 */

/* workspace layout for the bf16-gather path */
#define OFS_STATS 0u
#define OFS_FB16  4096u
#define WS_BF16  ((size_t)OFS_FB16 + (size_t)NPTS * CIN * 2)   /* ~19.2 MB */

/* bf16 helpers */
__device__ inline unsigned short f2b(float x) {
    unsigned u = __float_as_uint(x);
    u += 0x7FFFu + ((u >> 16) & 1u);
    return (unsigned short)(u >> 16);
}
__device__ inline float b2f_lo(unsigned d) { return __uint_as_float(d << 16); }
__device__ inline float b2f_hi(unsigned d) { return __uint_as_float(d & 0xFFFF0000u); }

/* ---------------- zero ---------------- */
__global__ __launch_bounds__(256) void zero_kernel(float4* __restrict__ out4, int n4,
                                                   float* __restrict__ stats) {
    int i = blockIdx.x * blockDim.x + threadIdx.x;
    if (i < n4) out4[i] = make_float4(0.f, 0.f, 0.f, 0.f);
    if (blockIdx.x == 0 && threadIdx.x < 16) stats[threadIdx.x] = 0.f;
}

/* ---------------- feats -> bf16 ---------------- */
__global__ __launch_bounds__(256) void to_bf16_kernel(const float2* __restrict__ src,
                                                      unsigned* __restrict__ dst, int n2) {
    int i = blockIdx.x * 256 + threadIdx.x;
    if (i < n2) {
        float2 v = src[i];
        dst[i] = (unsigned)f2b(v.x) | ((unsigned)f2b(v.y) << 16);
    }
}

/* ---------------- conv, bf16 gather ----------------
 * wave = pair stream for one offset k; lane = output channel.
 * w[] pinned in VGPRs via empty asm (prevents the compiler sinking the
 * loop-invariant weight loads into the pair loop -> 21.6 GB L2 traffic,
 * the round-1/2 bottleneck: VGPR_Count was 24, w[32] not resident).
 */
__global__ __launch_bounds__(256) void conv_bf16_kernel(
    const unsigned* __restrict__ fb16, const float* __restrict__ weight,
    const int* __restrict__ in_idx, const int* __restrict__ out_idx,
    float* __restrict__ out)
{
    const int lane = threadIdx.x & 63;
    const int wave = threadIdx.x >> 6;
    const int k     = blockIdx.x / BLOCKS_PER_K;
    const int pair0 = (blockIdx.x % BLOCKS_PER_K) * PAIRS_PER_BLOCK;

    float w[CIN];
    const float* wk = weight + k * (CIN * COUT) + lane;
#pragma unroll
    for (int i = 0; i < CIN; ++i) w[i] = wk[i * COUT];
#pragma unroll
    for (int i = 0; i < CIN; ++i) asm volatile("" : "+v"(w[i]));  /* pin in VGPRs */

    const int per_wave = PAIRS_PER_BLOCK / 4;
    int p    = pair0 + wave * per_wave;
    int pend = p + per_wave;
    if (pend > NPAIRS) pend = NPAIRS;

    const int* ii = in_idx  + k * NPAIRS;
    const int* oi = out_idx + k * NPAIRS;

#pragma unroll 2
    for (; p < pend; ++p) {
        int rin  = __builtin_amdgcn_readfirstlane(ii[p]);
        int rout = __builtin_amdgcn_readfirstlane(oi[p]);
        const unsigned* fr = fb16 + (size_t)rin * (CIN / 2);  /* 64B row, uniform */
        float acc = 0.f;
#pragma unroll
        for (int j = 0; j < CIN / 2; ++j) {
            unsigned d = fr[j];
            acc = fmaf(b2f_lo(d), w[2 * j],     acc);
            acc = fmaf(b2f_hi(d), w[2 * j + 1], acc);
        }
        atomicAdd(out + (size_t)rout * COUT + lane, acc);
    }
}

/* ---------------- conv, fp32 gather (no-ws fallback) ---------------- */
__global__ __launch_bounds__(256) void conv_f32_kernel(
    const float* __restrict__ feats, const float* __restrict__ weight,
    const int* __restrict__ in_idx, const int* __restrict__ out_idx,
    float* __restrict__ out)
{
    const int lane = threadIdx.x & 63;
    const int wave = threadIdx.x >> 6;
    const int k     = blockIdx.x / BLOCKS_PER_K;
    const int pair0 = (blockIdx.x % BLOCKS_PER_K) * PAIRS_PER_BLOCK;

    float w[CIN];
    const float* wk = weight + k * (CIN * COUT) + lane;
#pragma unroll
    for (int i = 0; i < CIN; ++i) w[i] = wk[i * COUT];
#pragma unroll
    for (int i = 0; i < CIN; ++i) asm volatile("" : "+v"(w[i]));

    const int per_wave = PAIRS_PER_BLOCK / 4;
    int p    = pair0 + wave * per_wave;
    int pend = p + per_wave;
    if (pend > NPAIRS) pend = NPAIRS;

    const int* ii = in_idx  + k * NPAIRS;
    const int* oi = out_idx + k * NPAIRS;

#pragma unroll 2
    for (; p < pend; ++p) {
        int rin  = __builtin_amdgcn_readfirstlane(ii[p]);
        int rout = __builtin_amdgcn_readfirstlane(oi[p]);
        const float* frow = feats + (size_t)rin * CIN;
        float acc = 0.f;
#pragma unroll
        for (int i = 0; i < CIN; ++i)
            acc = fmaf(frow[i], w[i], acc);
        atomicAdd(out + (size_t)rout * COUT + lane, acc);
    }
}

/* ---------------- group stats ---------------- */
__global__ __launch_bounds__(256) void stats_kernel(const float* __restrict__ out,
                                                    float* __restrict__ stats) {
    const int c = threadIdx.x & 63;
    const int wave_in_grid = blockIdx.x * 4 + (threadIdx.x >> 6);
    const int nwaves = gridDim.x * 4;
    float s = 0.f, ss = 0.f;
    for (int r = wave_in_grid; r < NPTS; r += nwaves) {
        float v = out[(size_t)r * COUT + c];
        s += v; ss += v * v;
    }
#pragma unroll
    for (int m = 1; m < 8; m <<= 1) {
        s  += __shfl_xor(s,  m, 64);
        ss += __shfl_xor(ss, m, 64);
    }
    if ((c & 7) == 0) {
        int g = c >> 3;
        atomicAdd(stats + g,     s);
        atomicAdd(stats + 8 + g, ss);
    }
}

/* ---------------- normalize + affine + leaky relu ---------------- */
__global__ __launch_bounds__(256) void norm_kernel(float4* __restrict__ out4, int n4,
                                                   const float* __restrict__ stats,
                                                   const float* __restrict__ gamma,
                                                   const float* __restrict__ beta) {
    int i = blockIdx.x * blockDim.x + threadIdx.x;
    if (i >= n4) return;
    int c0 = (i & 15) * 4;
    int g  = c0 >> 3;
    const float cnt = (float)NPTS * (COUT / NGROUP);
    float mean = stats[g] / cnt;
    float var  = stats[8 + g] / cnt - mean * mean;
    float inv  = rsqrtf(var + EPSV);
    float4 v  = out4[i];
    float4 ga = *(const float4*)(gamma + c0);
    float4 be = *(const float4*)(beta  + c0);
    float x;
    x = (v.x - mean) * inv * ga.x + be.x; v.x = x >= 0.f ? x : SLOPE * x;
    x = (v.y - mean) * inv * ga.y + be.y; v.y = x >= 0.f ? x : SLOPE * x;
    x = (v.z - mean) * inv * ga.z + be.z; v.z = x >= 0.f ? x : SLOPE * x;
    x = (v.w - mean) * inv * ga.w + be.w; v.w = x >= 0.f ? x : SLOPE * x;
    out4[i] = v;
}

/* ---------------- launch ---------------- */
extern "C" void kernel_launch(void* const* d_in, const int* in_sizes, int n_in,
                              void* d_out, int out_size, void* d_ws, size_t ws_size,
                              hipStream_t stream) {
    const float* feats   = (const float*)d_in[0];
    const float* weight  = (const float*)d_in[1];
    const float* gamma   = (const float*)d_in[2];
    const float* beta    = (const float*)d_in[3];
    const int*   in_idx  = (const int*)d_in[4];
    const int*   out_idx = (const int*)d_in[5];
    float* out = (float*)d_out;

    char* ws = (char*)d_ws;
    float*    stats = (float*)(ws + OFS_STATS);
    unsigned* fb16  = (unsigned*)(ws + OFS_FB16);

    int n4 = out_size / 4;
    int zb = (n4 + 255) / 256;

    zero_kernel<<<zb, 256, 0, stream>>>((float4*)out, n4, stats);

    if (ws_size >= WS_BF16) {
        int n2 = NPTS * CIN / 2;
        to_bf16_kernel<<<(n2 + 255) / 256, 256, 0, stream>>>((const float2*)feats, fb16, n2);
        conv_bf16_kernel<<<KOFF * BLOCKS_PER_K, 256, 0, stream>>>(fb16, weight, in_idx, out_idx, out);
    } else {
        conv_f32_kernel<<<KOFF * BLOCKS_PER_K, 256, 0, stream>>>(feats, weight, in_idx, out_idx, out);
    }

    stats_kernel<<<2048, 256, 0, stream>>>(out, stats);
    norm_kernel<<<zb, 256, 0, stream>>>((float4*)out, n4, stats, gamma, beta);
}

// Round 4
// 847.106 us; speedup vs baseline: 1.0906x; 1.0906x over previous
//
#include <hip/hip_runtime.h>

#define NPTS   300000
#define NPAIRS 100000
#define KOFF   27
#define NTOT   (KOFF * NPAIRS)      /* 2,700,000 */
#define CIN    32
#define COUT   64
#define NGROUP 8
#define EPSV   1e-5f
#define SLOPE  0.01f

#define PAIRS_PER_BLOCK 256
#define BLOCKS_PER_K ((NPAIRS + PAIRS_PER_BLOCK - 1) / PAIRS_PER_BLOCK)  /* 391 */
#define NB1 293                      /* ceil(300000/1024) */

/* ---- workspace layout (main CSR path) ---- */
#define OFS_STATS  0u
#define OFS_CURSOR 4096u                         /* 300000*4 = 1,200,000 */
#define OFS_PART   (OFS_CURSOR + 1204224u)       /* 4KB for partials */
#define OFS_ENT    (OFS_PART + 4096u)            /* 2.7M*4 = 10,800,000 */
#define OFS_FH16   (OFS_ENT + 10850304u)         /* 64B aligned */
#define WS_MAIN    ((size_t)OFS_FH16 + 19200000u)   /* ~31.3 MB */
/* fallback (round-3) layout */
#define OFS_FB16_FB 4096u
#define WS_BF16_FB ((size_t)OFS_FB16_FB + 19200000u)

/* ---- f16 / bf16 helpers ---- */
typedef _Float16 half2v __attribute__((ext_vector_type(2)));

__device__ inline unsigned pack_h2(float a, float b) {
    union { _Float16 h[2]; unsigned u; } x;
    x.h[0] = (_Float16)a; x.h[1] = (_Float16)b;   /* v_cvt_f16_f32, RNE */
    return x.u;
}
__device__ inline half2v as_h2(unsigned u) {
    union { unsigned u; half2v h; } x; x.u = u; return x.h;
}
__device__ inline float dot2_h(unsigned a, unsigned b, float c) {
#if __has_builtin(__builtin_amdgcn_fdot2)
    return __builtin_amdgcn_fdot2(as_h2(a), as_h2(b), c, false);
#else
    half2v ha = as_h2(a), hb = as_h2(b);
    c = fmaf((float)ha.x, (float)hb.x, c);
    return fmaf((float)ha.y, (float)hb.y, c);
#endif
}
__device__ inline unsigned short f2b(float x) {
    unsigned u = __float_as_uint(x);
    u += 0x7FFFu + ((u >> 16) & 1u);
    return (unsigned short)(u >> 16);
}
__device__ inline float b2f_lo(unsigned d) { return __uint_as_float(d << 16); }
__device__ inline float b2f_hi(unsigned d) { return __uint_as_float(d & 0xFFFF0000u); }

/* ================= build kernels ================= */

__global__ __launch_bounds__(256) void to_f16_kernel(const float2* __restrict__ src,
                                                     unsigned* __restrict__ dst, int n2) {
    int i = blockIdx.x * 256 + threadIdx.x;
    if (i < n2) { float2 v = src[i]; dst[i] = pack_h2(v.x, v.y); }
}

__global__ __launch_bounds__(256) void zero_aux_kernel(int* __restrict__ cursor,
                                                       float* __restrict__ stats) {
    int i = blockIdx.x * 256 + threadIdx.x;
    if (i < NPTS) cursor[i] = 0;
    if (blockIdx.x == 0 && threadIdx.x < 16) stats[threadIdx.x] = 0.f;
}

__global__ __launch_bounds__(256) void hist_kernel(const int* __restrict__ oi,
                                                   int* __restrict__ cursor) {
    int i = blockIdx.x * 256 + threadIdx.x;
    if (i < NTOT) atomicAdd(cursor + oi[i], 1);
}

__global__ __launch_bounds__(256) void reduce_blocks_kernel(const int* __restrict__ cursor,
                                                            int* __restrict__ part) {
    __shared__ int sm[256];
    int tid = threadIdx.x, i0 = blockIdx.x * 1024 + tid * 4;
    int s = 0;
#pragma unroll
    for (int j = 0; j < 4; ++j) if (i0 + j < NPTS) s += cursor[i0 + j];
    sm[tid] = s; __syncthreads();
    for (int off = 128; off; off >>= 1) {
        if (tid < off) sm[tid] += sm[tid + off];
        __syncthreads();
    }
    if (tid == 0) part[blockIdx.x] = sm[0];
}

__global__ __launch_bounds__(512) void scan_partials_kernel(int* __restrict__ part) {
    __shared__ int sm[512];
    int tid = threadIdx.x;
    int v = (tid < NB1) ? part[tid] : 0;
    sm[tid] = v; __syncthreads();
    for (int off = 1; off < 512; off <<= 1) {
        int t = (tid >= off) ? sm[tid - off] : 0;
        __syncthreads();
        sm[tid] += t;
        __syncthreads();
    }
    if (tid < NB1) part[tid] = sm[tid] - v;   /* exclusive */
}

__global__ __launch_bounds__(256) void scan_apply_kernel(int* __restrict__ cursor,
                                                         const int* __restrict__ part) {
    __shared__ int sm[256];
    int tid = threadIdx.x, i0 = blockIdx.x * 1024 + tid * 4;
    int c0 = 0, c1 = 0, c2 = 0, c3 = 0;
    if (i0 + 0 < NPTS) c0 = cursor[i0 + 0];
    if (i0 + 1 < NPTS) c1 = cursor[i0 + 1];
    if (i0 + 2 < NPTS) c2 = cursor[i0 + 2];
    if (i0 + 3 < NPTS) c3 = cursor[i0 + 3];
    int s = c0 + c1 + c2 + c3;
    sm[tid] = s; __syncthreads();
    for (int off = 1; off < 256; off <<= 1) {
        int t = (tid >= off) ? sm[tid - off] : 0;
        __syncthreads();
        sm[tid] += t;
        __syncthreads();
    }
    int excl = sm[tid] - s + part[blockIdx.x];
    if (i0 + 0 < NPTS) cursor[i0 + 0] = excl;
    if (i0 + 1 < NPTS) cursor[i0 + 1] = excl + c0;
    if (i0 + 2 < NPTS) cursor[i0 + 2] = excl + c0 + c1;
    if (i0 + 3 < NPTS) cursor[i0 + 3] = excl + c0 + c1 + c2;
}

/* entries[slot] = rin | k<<19 ; after this, cursor[r] = row end */
__global__ __launch_bounds__(256) void fill_kernel(const int* __restrict__ oi,
                                                   const int* __restrict__ ii,
                                                   int* __restrict__ cursor,
                                                   unsigned* __restrict__ entries) {
    int i = blockIdx.x * 256 + threadIdx.x;
    if (i < NTOT) {
        int k = i / NPAIRS;
        int slot = atomicAdd(cursor + oi[i], 1);
        entries[slot] = (unsigned)ii[i] | ((unsigned)k << 19);
    }
}

/* ================= CSR conv: row-owned accumulate, no output atomics =================
 * block = 1024 thr (16 waves), all 27 f16 weight matrices in LDS (110,592 B).
 * wave owns a contiguous chunk of rows; lane = output channel.
 * Per entry: uniform 64B f16 feats row + 16 ds_read_b32 + 16 v_dot2_f32_f16.
 * Group stats fused (per-lane running sum/sumsq -> 8-lane shfl -> atomic).
 */
__global__ __launch_bounds__(1024) void conv_csr_kernel(
    const unsigned* __restrict__ fh16, const float* __restrict__ weight,
    const unsigned* __restrict__ entries, const int* __restrict__ ends,
    float* __restrict__ out, float* __restrict__ stats)
{
    __shared__ unsigned lds_w[KOFF * 16 * 64];
    const int tid = threadIdx.x;
    for (int d = tid; d < KOFF * 1024; d += 1024) {
        int k = d >> 10, rem = d & 1023, j = rem >> 6, c = rem & 63;
        const float* wp = weight + k * (CIN * COUT) + (2 * j) * COUT + c;
        lds_w[d] = pack_h2(wp[0], wp[COUT]);
    }
    __syncthreads();

    const int lane = tid & 63;
    const int gw   = blockIdx.x * 16 + (tid >> 6);   /* global wave id, 4096 total */
    const int chunk = (NPTS + 4095) / 4096;          /* 74 rows per wave */
    int rbeg = gw * chunk;
    int rend = rbeg + chunk; if (rend > NPTS) rend = NPTS;

    float ssum = 0.f, ssq = 0.f;

    if (rbeg < NPTS) {
        int s = (rbeg == 0) ? 0 : ends[rbeg - 1];
        s = __builtin_amdgcn_readfirstlane(s);
        for (int r = rbeg; r < rend; ++r) {
            int e = __builtin_amdgcn_readfirstlane(ends[r]);
            float acc = 0.f;
            if (s < e) {
                unsigned ent = __builtin_amdgcn_readfirstlane(entries[s]);
                unsigned f[16];
                {
                    const unsigned* fr = fh16 + (size_t)(ent & 0x7FFFFu) * 16;
#pragma unroll
                    for (int j = 0; j < 16; ++j) f[j] = fr[j];
                }
                for (int t = s; t < e; ++t) {
                    unsigned nent = (t + 1 < e)
                        ? __builtin_amdgcn_readfirstlane(entries[t + 1]) : ent;
                    unsigned g[16];
                    const unsigned* nr = fh16 + (size_t)(nent & 0x7FFFFu) * 16;
#pragma unroll
                    for (int j = 0; j < 16; ++j) g[j] = nr[j];   /* prefetch next row */
                    int kk = ent >> 19;
                    const unsigned* wl = lds_w + (kk << 10) + lane;
#pragma unroll
                    for (int j = 0; j < 16; ++j)
                        acc = dot2_h(f[j], wl[j << 6], acc);
#pragma unroll
                    for (int j = 0; j < 16; ++j) f[j] = g[j];
                    ent = nent;
                }
            }
            out[(size_t)r * COUT + lane] = acc;      /* coalesced 256B row store */
            ssum += acc; ssq += acc * acc;
            s = e;
        }
    }
#pragma unroll
    for (int m = 1; m < 8; m <<= 1) {
        ssum += __shfl_xor(ssum, m, 64);
        ssq  += __shfl_xor(ssq,  m, 64);
    }
    if ((lane & 7) == 0) {
        int g = lane >> 3;
        atomicAdd(stats + g,     ssum);
        atomicAdd(stats + 8 + g, ssq);
    }
}

/* ================= normalize + affine + leaky relu ================= */
__global__ __launch_bounds__(256) void norm_kernel(float4* __restrict__ out4, int n4,
                                                   const float* __restrict__ stats,
                                                   const float* __restrict__ gamma,
                                                   const float* __restrict__ beta) {
    int i = blockIdx.x * blockDim.x + threadIdx.x;
    if (i >= n4) return;
    int c0 = (i & 15) * 4;
    int g  = c0 >> 3;
    const float cnt = (float)NPTS * (COUT / NGROUP);
    float mean = stats[g] / cnt;
    float var  = stats[8 + g] / cnt - mean * mean;
    float inv  = rsqrtf(var + EPSV);
    float4 v  = out4[i];
    float4 ga = *(const float4*)(gamma + c0);
    float4 be = *(const float4*)(beta  + c0);
    float x;
    x = (v.x - mean) * inv * ga.x + be.x; v.x = x >= 0.f ? x : SLOPE * x;
    x = (v.y - mean) * inv * ga.y + be.y; v.y = x >= 0.f ? x : SLOPE * x;
    x = (v.z - mean) * inv * ga.z + be.z; v.z = x >= 0.f ? x : SLOPE * x;
    x = (v.w - mean) * inv * ga.w + be.w; v.w = x >= 0.f ? x : SLOPE * x;
    out4[i] = v;
}

/* ================= fallback kernels (round-3 path) ================= */
__global__ __launch_bounds__(256) void zero_kernel(float4* __restrict__ out4, int n4,
                                                   float* __restrict__ stats) {
    int i = blockIdx.x * blockDim.x + threadIdx.x;
    if (i < n4) out4[i] = make_float4(0.f, 0.f, 0.f, 0.f);
    if (blockIdx.x == 0 && threadIdx.x < 16) stats[threadIdx.x] = 0.f;
}

__global__ __launch_bounds__(256) void to_bf16_kernel(const float2* __restrict__ src,
                                                      unsigned* __restrict__ dst, int n2) {
    int i = blockIdx.x * 256 + threadIdx.x;
    if (i < n2) {
        float2 v = src[i];
        dst[i] = (unsigned)f2b(v.x) | ((unsigned)f2b(v.y) << 16);
    }
}

__global__ __launch_bounds__(256) void conv_bf16_kernel(
    const unsigned* __restrict__ fb16, const float* __restrict__ weight,
    const int* __restrict__ in_idx, const int* __restrict__ out_idx,
    float* __restrict__ out)
{
    const int lane = threadIdx.x & 63;
    const int wave = threadIdx.x >> 6;
    const int k     = blockIdx.x / BLOCKS_PER_K;
    const int pair0 = (blockIdx.x % BLOCKS_PER_K) * PAIRS_PER_BLOCK;
    float w[CIN];
    const float* wk = weight + k * (CIN * COUT) + lane;
#pragma unroll
    for (int i = 0; i < CIN; ++i) w[i] = wk[i * COUT];
    const int per_wave = PAIRS_PER_BLOCK / 4;
    int p = pair0 + wave * per_wave;
    int pend = p + per_wave; if (pend > NPAIRS) pend = NPAIRS;
    const int* ii = in_idx  + k * NPAIRS;
    const int* oi = out_idx + k * NPAIRS;
    for (; p < pend; ++p) {
        int rin  = __builtin_amdgcn_readfirstlane(ii[p]);
        int rout = __builtin_amdgcn_readfirstlane(oi[p]);
        const unsigned* fr = fb16 + (size_t)rin * (CIN / 2);
        float acc = 0.f;
#pragma unroll
        for (int j = 0; j < CIN / 2; ++j) {
            unsigned d = fr[j];
            acc = fmaf(b2f_lo(d), w[2 * j],     acc);
            acc = fmaf(b2f_hi(d), w[2 * j + 1], acc);
        }
        atomicAdd(out + (size_t)rout * COUT + lane, acc);
    }
}

__global__ __launch_bounds__(256) void conv_f32_kernel(
    const float* __restrict__ feats, const float* __restrict__ weight,
    const int* __restrict__ in_idx, const int* __restrict__ out_idx,
    float* __restrict__ out)
{
    const int lane = threadIdx.x & 63;
    const int wave = threadIdx.x >> 6;
    const int k     = blockIdx.x / BLOCKS_PER_K;
    const int pair0 = (blockIdx.x % BLOCKS_PER_K) * PAIRS_PER_BLOCK;
    float w[CIN];
    const float* wk = weight + k * (CIN * COUT) + lane;
#pragma unroll
    for (int i = 0; i < CIN; ++i) w[i] = wk[i * COUT];
    const int per_wave = PAIRS_PER_BLOCK / 4;
    int p = pair0 + wave * per_wave;
    int pend = p + per_wave; if (pend > NPAIRS) pend = NPAIRS;
    const int* ii = in_idx  + k * NPAIRS;
    const int* oi = out_idx + k * NPAIRS;
    for (; p < pend; ++p) {
        int rin  = __builtin_amdgcn_readfirstlane(ii[p]);
        int rout = __builtin_amdgcn_readfirstlane(oi[p]);
        const float* frow = feats + (size_t)rin * CIN;
        float acc = 0.f;
#pragma unroll
        for (int i = 0; i < CIN; ++i) acc = fmaf(frow[i], w[i], acc);
        atomicAdd(out + (size_t)rout * COUT + lane, acc);
    }
}

__global__ __launch_bounds__(256) void stats_kernel(const float* __restrict__ out,
                                                    float* __restrict__ stats) {
    const int c = threadIdx.x & 63;
    const int wave_in_grid = blockIdx.x * 4 + (threadIdx.x >> 6);
    const int nwaves = gridDim.x * 4;
    float s = 0.f, ss = 0.f;
    for (int r = wave_in_grid; r < NPTS; r += nwaves) {
        float v = out[(size_t)r * COUT + c];
        s += v; ss += v * v;
    }
#pragma unroll
    for (int m = 1; m < 8; m <<= 1) {
        s  += __shfl_xor(s,  m, 64);
        ss += __shfl_xor(ss, m, 64);
    }
    if ((c & 7) == 0) {
        int g = c >> 3;
        atomicAdd(stats + g,     s);
        atomicAdd(stats + 8 + g, ss);
    }
}

/* ================= launch ================= */
extern "C" void kernel_launch(void* const* d_in, const int* in_sizes, int n_in,
                              void* d_out, int out_size, void* d_ws, size_t ws_size,
                              hipStream_t stream) {
    const float* feats   = (const float*)d_in[0];
    const float* weight  = (const float*)d_in[1];
    const float* gamma   = (const float*)d_in[2];
    const float* beta    = (const float*)d_in[3];
    const int*   in_idx  = (const int*)d_in[4];
    const int*   out_idx = (const int*)d_in[5];
    float* out = (float*)d_out;
    char*  ws  = (char*)d_ws;

    int n4 = out_size / 4;
    int zb = (n4 + 255) / 256;
    int n2 = NPTS * CIN / 2;

    if (ws_size >= WS_MAIN) {
        float*    stats   = (float*)(ws + OFS_STATS);
        int*      cursor  = (int*)(ws + OFS_CURSOR);
        int*      part    = (int*)(ws + OFS_PART);
        unsigned* entries = (unsigned*)(ws + OFS_ENT);
        unsigned* fh16    = (unsigned*)(ws + OFS_FH16);

        to_f16_kernel<<<(n2 + 255) / 256, 256, 0, stream>>>((const float2*)feats, fh16, n2);
        zero_aux_kernel<<<(NPTS + 255) / 256, 256, 0, stream>>>(cursor, (float*)(ws + OFS_STATS));
        hist_kernel<<<(NTOT + 255) / 256, 256, 0, stream>>>(out_idx, cursor);
        reduce_blocks_kernel<<<NB1, 256, 0, stream>>>(cursor, part);
        scan_partials_kernel<<<1, 512, 0, stream>>>(part);
        scan_apply_kernel<<<NB1, 256, 0, stream>>>(cursor, part);
        fill_kernel<<<(NTOT + 255) / 256, 256, 0, stream>>>(out_idx, in_idx, cursor, entries);
        conv_csr_kernel<<<256, 1024, 0, stream>>>(fh16, weight, entries, cursor, out, stats);
        norm_kernel<<<zb, 256, 0, stream>>>((float4*)out, n4, stats, gamma, beta);
    } else if (ws_size >= WS_BF16_FB) {
        float*    stats = (float*)(ws + OFS_STATS);
        unsigned* fb16  = (unsigned*)(ws + OFS_FB16_FB);
        zero_kernel<<<zb, 256, 0, stream>>>((float4*)out, n4, stats);
        to_bf16_kernel<<<(n2 + 255) / 256, 256, 0, stream>>>((const float2*)feats, fb16, n2);
        conv_bf16_kernel<<<KOFF * BLOCKS_PER_K, 256, 0, stream>>>(fb16, weight, in_idx, out_idx, out);
        stats_kernel<<<2048, 256, 0, stream>>>(out, stats);
        norm_kernel<<<zb, 256, 0, stream>>>((float4*)out, n4, stats, gamma, beta);
    } else {
        float* stats = (float*)(ws + OFS_STATS);
        zero_kernel<<<zb, 256, 0, stream>>>((float4*)out, n4, stats);
        conv_f32_kernel<<<KOFF * BLOCKS_PER_K, 256, 0, stream>>>(feats, weight, in_idx, out_idx, out);
        stats_kernel<<<2048, 256, 0, stream>>>(out, stats);
        norm_kernel<<<zb, 256, 0, stream>>>((float4*)out, n4, stats, gamma, beta);
    }
}